// Round 9
// baseline (8531.992 us; speedup 1.0000x reference)
//
#include <hip/hip_runtime.h>
#include <math.h>

#define NG 256        // grid blocks
#define NT 512        // threads per block
#define XS2 1032      // LDS x stride in floats (16B-aligned, odd 32-group)
#define NLOGW 250     // logits blocks (32 vocab rows each)

// ---------------------------------------------------------------------------
// Producers write mutable state via LLC-direct store (sc0 sc1). Buffers are
// WRITE-ONCE per launch (64-step versioned), so consumers may use plain
// cached loads: no L1/L2 line can hold a pre-write value (first touch is
// always post-producing-barrier), and the AQL dispatch acquire invalidates
// caches between graph replays.
// ---------------------------------------------------------------------------
__device__ __forceinline__ void stc(float* p, float v) {
    __hip_atomic_store(p, v, __ATOMIC_RELAXED, __HIP_MEMORY_SCOPE_AGENT);
}

// Round-5 barrier (best measured): 16 arrival lines -> c1 -> go, throttled spin.
__device__ __forceinline__ void gbar(int* cnt, int epoch, int g, int tid) {
    __syncthreads();   // compiler emits vmcnt(0) drain before s_barrier
    if (tid == 0) {
        int* c0 = cnt + ((g & 15) << 5);
        int* c1 = cnt + 512;
        int* go = cnt + 576;
        int r = __hip_atomic_fetch_add(c0, 1, __ATOMIC_RELAXED,
                                       __HIP_MEMORY_SCOPE_AGENT);
        if (r == (epoch << 4) - 1) {
            int r2 = __hip_atomic_fetch_add(c1, 1, __ATOMIC_RELAXED,
                                            __HIP_MEMORY_SCOPE_AGENT);
            if (r2 == (epoch << 4) - 1)
                __hip_atomic_store(go, epoch, __ATOMIC_RELAXED,
                                   __HIP_MEMORY_SCOPE_AGENT);
        }
        int it = 0;
        while (__hip_atomic_load(go, __ATOMIC_RELAXED,
                                 __HIP_MEMORY_SCOPE_AGENT) < epoch)
            if (++it > 4) __builtin_amdgcn_s_sleep(8);
    }
    __syncthreads();
}

__device__ __forceinline__ void merge3(float& M, float& S, float& I,
                                       float m, float se, float ii) {
    if (m > M)       { S = S * expf(M - m) + se; M = m; I = ii; }
    else if (m == M) { S += se; if (ii < I) I = ii; }
    else             { S += se * expf(m - M); }
}

// ---------------------------------------------------------------------------
// Vv[b,t,a] = sum_d enc[b,t,d] * attn_V[a,d]   (one-time precompute)
// ---------------------------------------------------------------------------
__global__ __launch_bounds__(256) void k_vv(const float* __restrict__ enc,
                                            const float* __restrict__ attn_V,
                                            float* __restrict__ Vv) {
    int wg = blockIdx.x;
    int b = wg / 40, t0 = (wg % 40) * 15;
    int tid = threadIdx.x;
    __shared__ __align__(16) float encL[15][512];
    for (int i = tid; i < 15 * 512; i += 256) {
        int tl = i >> 9, d = i & 511;
        encL[tl][d] = enc[((size_t)(b * 600) + (t0 + tl)) * 512 + d];
    }
    __syncthreads();
    for (int half = 0; half < 2; ++half) {
        int a = tid + half * 256;
        const float4* wrow = reinterpret_cast<const float4*>(attn_V + (size_t)a * 512);
        float acc[15];
#pragma unroll
        for (int tl = 0; tl < 15; ++tl) acc[tl] = 0.f;
        for (int k = 0; k < 128; ++k) {
            float4 w = wrow[k];
#pragma unroll
            for (int tl = 0; tl < 15; ++tl) {
                float4 x = reinterpret_cast<const float4*>(&encL[tl][0])[k];
                acc[tl] += w.x * x.x + w.y * x.y + w.z * x.z + w.w * x.w;
            }
        }
        for (int tl = 0; tl < 15; ++tl)
            Vv[((size_t)(b * 600) + (t0 + tl)) * 512 + a] = acc[tl];
    }
}

// ---------------------------------------------------------------------------
// Persistent kernel: all 64 decode steps. Versioned (write-once) state.
// ---------------------------------------------------------------------------
__global__ __launch_bounds__(NT, 1) void mega(
    const float* __restrict__ enc, const float* __restrict__ emb,
    const float* __restrict__ w_ih, const float* __restrict__ w_hh,
    const float* __restrict__ b_ih, const float* __restrict__ b_hh,
    const float* __restrict__ conv_w, const float* __restrict__ conv_b,
    const float* __restrict__ attn_W, const float* __restrict__ attn_fc_w,
    const float* __restrict__ attn_fc_b, const float* __restrict__ attn_b,
    const float* __restrict__ fc_w, const float* __restrict__ fc_b,
    const float* __restrict__ Vv, const float* __restrict__ Z,
    float* hv, float* cv, float* wqv, float* scv, float* awv, float* pav,
    float* logZ, int* cnt, float* dout)
{
    const int g = blockIdx.x;
    const int tid = threadIdx.x;
    const int bg = g & 15;
    int ep = 0;

    __shared__ __align__(16) float xs[16 * XS2];   // 64.5 KB staging
    __shared__ float aux[2600];                    // pg | tokf@2048 | wred@2064/2080 | red16@0

    for (int s = 0; s < 64; ++s) {
        const float* h_r   = (s == 0) ? Z         : hv + (size_t)(s - 1) * 8192;
        const float* ctx_r = (s == 0) ? Z + 8192  : cv + (size_t)(s - 1) * 8192;
        const float* aw_r  = (s == 0) ? Z + 16384 : awv + (size_t)(s - 1) * 9600;
        float* h_w   = hv  + (size_t)s * 8192;
        float* ctx_w = cv  + (size_t)s * 8192;
        float* aw_w  = awv + (size_t)s * 9600;
        float* wq_s  = wqv + (size_t)s * 8192;
        float* sc_s  = scv + (size_t)s * 9600;
        float* pa_w  = pav + (size_t)s * 16384;

        // ========== phase1: token finalize + GRU (2 h-indices/block) ==========
        {
            float* pg = aux;            // [4][512] gate partials
            float* tokf = aux + 2048;   // [16]
            if (s == 0) {
                if (tid < 16) tokf[tid] = 1.0f;   // SOS
                __syncthreads();
            } else {
                const float* pa_r = pav + (size_t)(s - 1) * 16384;
                const int wv = tid >> 6, lane = tid & 63;
                for (int b = wv; b < 16; b += 8) {
                    float M = -3.4e38f, S = 0.f, I = 0.f;
                    for (int q = 0; q < 4; ++q) {
                        int pw = lane + (q << 6);
                        if (pw < NLOGW) {
                            const float* r = pa_r + ((size_t)pw * 16 + b) * 4;
                            merge3(M, S, I, r[0], r[1], r[2]);
                        }
                    }
                    for (int off = 32; off; off >>= 1)
                        merge3(M, S, I, __shfl_xor(M, off, 64),
                               __shfl_xor(S, off, 64), __shfl_xor(I, off, 64));
                    if (lane == 0) {
                        tokf[b] = I;
                        if (g == 0) stc(&logZ[(s - 1) * 16 + b], M + logf(S));
                    }
                }
                __syncthreads();
            }
            // GRU: block g owns h-indices i = 2g, 2g+1 for all 16 b.
            const int b  = tid & 15;
            const int u  = tid >> 4;        // [0,32)
            const int il = u & 1;
            const int pr = u >> 1;          // [0,16) -> 32-float k-slice
            const int i  = (g << 1) + il;
            float ar = 0.f, az = 0.f, axn = 0.f, ahn = 0.f;
            for (int pass = 0; pass < 3; ++pass) {
                // stage 512 floats per b, vectorized float4
                for (int idx = tid; idx < 2048; idx += NT) {
                    int bb2 = idx >> 7, k4 = idx & 127;
                    float4 v4;
                    if (pass == 0)
                        v4 = ((const float4*)(emb + (size_t)((int)tokf[bb2]) * 512))[k4];
                    else if (pass == 1)
                        v4 = ((const float4*)(ctx_r + (bb2 << 9)))[k4];
                    else
                        v4 = ((const float4*)(h_r + (bb2 << 9)))[k4];
                    ((float4*)(xs + bb2 * XS2))[k4] = v4;
                }
                __syncthreads();
                const float* wbase = (pass == 2) ? w_hh : w_ih;
                const size_t rl = (pass == 2) ? 512 : 1024;
                const int ko = (pass == 1) ? 512 : 0;
                const float4* wr = (const float4*)(wbase + (size_t)i * rl + ko) + (pr << 3);
                const float4* wz = (const float4*)(wbase + (size_t)(512 + i) * rl + ko) + (pr << 3);
                const float4* wn = (const float4*)(wbase + (size_t)(1024 + i) * rl + ko) + (pr << 3);
                const float4* xv = (const float4*)(xs + b * XS2) + (pr << 3);
                float s0 = 0.f, s1 = 0.f, s2 = 0.f;
#pragma unroll
                for (int k = 0; k < 8; ++k) {
                    float4 x = xv[k];
                    float4 a = wr[k]; s0 += a.x*x.x + a.y*x.y + a.z*x.z + a.w*x.w;
                    float4 c = wz[k]; s1 += c.x*x.x + c.y*x.y + c.z*x.z + c.w*x.w;
                    float4 d = wn[k]; s2 += d.x*x.x + d.y*x.y + d.z*x.z + d.w*x.w;
                }
                ar += s0; az += s1;
                if (pass < 2) axn += s2; else ahn += s2;
                if (pass < 2) __syncthreads();
            }
            {
                int base = (((b << 1) + il) << 4) + pr;
                pg[base] = ar; pg[512 + base] = az;
                pg[1024 + base] = axn; pg[1536 + base] = ahn;
            }
            __syncthreads();
            if (tid < 32) {
                int bb = tid & 15, ill = tid >> 4;
                int ii = (g << 1) + ill;
                float sr = 0.f, sz2 = 0.f, sxn = 0.f, shn = 0.f;
                int bs2 = ((bb << 1) + ill) << 4;
                for (int q = 0; q < 16; ++q) {
                    sr  += pg[bs2 + q];        sz2 += pg[512 + bs2 + q];
                    sxn += pg[1024 + bs2 + q]; shn += pg[1536 + bs2 + q];
                }
                sr  += b_ih[ii] + b_hh[ii];
                sz2 += b_ih[512 + ii] + b_hh[512 + ii];
                sxn += b_ih[1024 + ii];
                shn += b_hh[1024 + ii];
                float r = 1.f / (1.f + expf(-sr));
                float z = 1.f / (1.f + expf(-sz2));
                float n = tanhf(sxn + r * shn);
                float hp = xs[bb * XS2 + ii];   // pass2 staged h_r
                stc(&h_w[(bb << 9) + ii], (1.f - z) * n + z * hp);
            }
        }
        gbar(cnt, ++ep, g, tid);   // h complete

        // ========== phase2: wq slice — b=bg, 32 a's per block ==========
        {
            const int ac = g >> 4;
            for (int idx = tid; idx < 128; idx += NT)
                ((float4*)xs)[idx] = ((const float4*)(h_w + (bg << 9)))[idx];
            __syncthreads();
            const int al = tid >> 4, ln = tid & 15;
            const int a = (ac << 5) + al;
            const float4* wr = (const float4*)(attn_W + (size_t)a * 512) + (ln << 3);
            const float4* hvv = (const float4*)xs + (ln << 3);
            float acc = 0.f;
#pragma unroll
            for (int k = 0; k < 8; ++k) {
                float4 w = wr[k], x = hvv[k];
                acc += w.x*x.x + w.y*x.y + w.z*x.z + w.w*x.w;
            }
            for (int off = 8; off; off >>= 1) acc += __shfl_xor(acc, off, 64);
            if (ln == 0) stc(&wq_s[(bg << 9) + a], acc);
        }
        gbar(cnt, ++ep, g, tid);   // wq complete

        // ========== phase3: scores — b=bg, 38 t per block ==========
        {
            const int tc = g >> 4;
            const int t0 = tc * 38;
            float* wqL  = xs;
            float* cw0  = xs + 512;
            float* cw1  = xs + 1024;
            float* cw2  = xs + 1536;
            float* cbab = xs + 2048;
            float* fcwL = xs + 2560;
            for (int a = tid; a < 512; a += NT) {
                wqL[a]  = wq_s[(bg << 9) + a];
                cw0[a]  = conv_w[a * 3];
                cw1[a]  = conv_w[a * 3 + 1];
                cw2[a]  = conv_w[a * 3 + 2];
                cbab[a] = conv_b[a] + attn_b[a];
                fcwL[a] = attn_fc_w[a];
            }
            __syncthreads();
            const float fcb = attn_fc_b[0];
            const int wv = tid >> 6, lane = tid & 63;
            for (int tl = wv; tl < 38; tl += 8) {
                const int t = t0 + tl;
                if (t < 600) {
                    const float awm = (t > 0)   ? aw_r[bg * 600 + t - 1] : 0.f;
                    const float aw0 = aw_r[bg * 600 + t];
                    const float awp = (t < 599) ? aw_r[bg * 600 + t + 1] : 0.f;
                    const float* vv = Vv + ((size_t)bg * 600 + t) * 512;
                    float acc = 0.f;
#pragma unroll
                    for (int q = 0; q < 8; ++q) {
                        const int a = lane + (q << 6);
                        float va = __builtin_nontemporal_load(vv + a);
                        float uu = wqL[a] + va + cbab[a]
                                 + cw0[a] * awm + cw1[a] * aw0 + cw2[a] * awp;
                        acc += tanhf(uu) * fcwL[a];
                    }
                    for (int off = 32; off; off >>= 1) acc += __shfl_xor(acc, off, 64);
                    if (lane == 0) stc(&sc_s[bg * 600 + t], acc + fcb);
                }
            }
        }
        gbar(cnt, ++ep, g, tid);   // scores complete

        // ========== phase4: softmax (redundant) + ctx e-slice ==========
        {
            const int ec = g >> 4;
            float* pb    = xs;          // [600]
            float* wredM = aux + 2064;  // [8]
            float* wredS = aux + 2080;  // [8]
            float* red16 = aux;         // [16][32]
            float lm = -3.4e38f;
            for (int t = tid; t < 600; t += NT) {
                float v = sc_s[bg * 600 + t];
                pb[t] = v;
                lm = fmaxf(lm, v);
            }
            for (int off = 32; off; off >>= 1) lm = fmaxf(lm, __shfl_xor(lm, off, 64));
            if ((tid & 63) == 0) wredM[tid >> 6] = lm;
            __syncthreads();
            float M = wredM[0];
#pragma unroll
            for (int q = 1; q < 8; ++q) M = fmaxf(M, wredM[q]);
            float lsum = 0.f;
            for (int t = tid; t < 600; t += NT) {
                float e = expf(pb[t] - M);
                pb[t] = e;
                lsum += e;
            }
            for (int off = 32; off; off >>= 1) lsum += __shfl_xor(lsum, off, 64);
            if ((tid & 63) == 0) wredS[tid >> 6] = lsum;
            __syncthreads();
            float S = 0.f;
#pragma unroll
            for (int q = 0; q < 8; ++q) S += wredS[q];
            const float invS = 1.f / S;
            if (ec == 0)
                for (int t = tid; t < 600; t += NT) stc(&aw_w[bg * 600 + t], pb[t] * invS);
            const int tg = tid >> 5, l32 = tid & 31;
            const int e = (ec << 5) + l32;
            float acc = 0.f;
            for (int t = tg; t < 600; t += 16)
                acc += pb[t] * __builtin_nontemporal_load(
                           enc + ((size_t)bg * 600 + t) * 512 + e);
            red16[(tg << 5) + l32] = acc;
            __syncthreads();
            if (tg == 0) {
                float a2 = 0.f;
#pragma unroll
                for (int q = 0; q < 16; ++q) a2 += red16[(q << 5) + l32];
                stc(&ctx_w[(bg << 9) + e], a2 * invS);
            }
        }
        gbar(cnt, ++ep, g, tid);   // ctx complete

        // ========== phase5: logits (1 row/thread, all 512 threads) ==========
        {
            const int jj = tid & 31;        // row within block's 32
            const int bb = tid >> 5;        // batch
            const int act = (g < NLOGW);
            const int v = (g << 5) + jj;
            // stage x = [h_w | ctx_w] for all 16 b (1024 floats per b)
            for (int idx = tid; idx < 2048; idx += NT) {
                int b2 = idx >> 7, k4 = idx & 127;
                ((float4*)(xs + b2 * XS2))[k4] =
                    ((const float4*)(h_w + (b2 << 9)))[k4];
                ((float4*)(xs + b2 * XS2 + 512))[k4] =
                    ((const float4*)(ctx_w + (b2 << 9)))[k4];
            }
            __syncthreads();
            if (act) {
                const float4* wrow = (const float4*)(fc_w + (size_t)v * 1024);
                const float4* xrow = (const float4*)(xs + bb * XS2);
                float a0 = 0.f, a1 = 0.f, a2 = 0.f, a3 = 0.f;
                for (int k = 0; k < 256; k += 4) {
                    float4 w0 = wrow[k],     x0 = xrow[k];
                    float4 w1 = wrow[k + 1], x1 = xrow[k + 1];
                    float4 w2 = wrow[k + 2], x2 = xrow[k + 2];
                    float4 w3 = wrow[k + 3], x3 = xrow[k + 3];
                    a0 += w0.x*x0.x + w0.y*x0.y + w0.z*x0.z + w0.w*x0.w;
                    a1 += w1.x*x1.x + w1.y*x1.y + w1.z*x1.z + w1.w*x1.w;
                    a2 += w2.x*x2.x + w2.y*x2.y + w2.z*x2.z + w2.w*x2.w;
                    a3 += w3.x*x3.x + w3.y*x3.y + w3.z*x3.z + w3.w*x3.w;
                }
                float acc = ((a0 + a1) + (a2 + a3)) + fc_b[v];
                stc(dout + ((size_t)bb * 64 + s) * 8000 + v, acc);
                // per-(block,b) partial {max, sumexp, argmin-idx} via shuffles
                float M = acc, S = 1.f, I = (float)v;
#pragma unroll
                for (int off = 1; off < 32; off <<= 1)
                    merge3(M, S, I, __shfl_xor(M, off, 64),
                           __shfl_xor(S, off, 64), __shfl_xor(I, off, 64));
                if (jj == 0) {
                    float* pr = pa_w + ((size_t)g * 16 + bb) * 4;
                    stc(pr, M); stc(pr + 1, S); stc(pr + 2, I);
                }
            }
        }
        gbar(cnt, ++ep, g, tid);   // partials complete
    }

    // ---- final logZ (s=63) ----
    if (g == 0) {
        const float* pa_r = pav + (size_t)63 * 16384;
        const int wv = tid >> 6, lane = tid & 63;
        for (int b = wv; b < 16; b += 8) {
            float M = -3.4e38f, S = 0.f, I = 0.f;
            for (int q = 0; q < 4; ++q) {
                int pw = lane + (q << 6);
                if (pw < NLOGW) {
                    const float* r = pa_r + ((size_t)pw * 16 + b) * 4;
                    merge3(M, S, I, r[0], r[1], r[2]);
                }
            }
            for (int off = 32; off; off >>= 1)
                merge3(M, S, I, __shfl_xor(M, off, 64),
                       __shfl_xor(S, off, 64), __shfl_xor(I, off, 64));
            if (lane == 0) stc(&logZ[63 * 16 + b], M + logf(S));
        }
    }
    gbar(cnt, ++ep, g, tid);
    // ---- normalize: logp = logits - logZ ----
    for (int r = g; r < 1024; r += NG) {          // r = b*64 + s
        float z = logZ[(r & 63) * 16 + (r >> 6)];
        float* o = dout + (size_t)r * 8000;
        for (int i = tid; i < 8000; i += NT) o[i] -= z;
    }
}

// ---------------------------------------------------------------------------
extern "C" void kernel_launch(void* const* d_in, const int* in_sizes, int n_in,
                              void* d_out, int out_size, void* d_ws, size_t ws_size,
                              hipStream_t stream) {
    const float* enc       = (const float*)d_in[0];
    const float* emb       = (const float*)d_in[1];
    const float* w_ih      = (const float*)d_in[2];
    const float* w_hh      = (const float*)d_in[3];
    const float* b_ih      = (const float*)d_in[4];
    const float* b_hh      = (const float*)d_in[5];
    const float* conv_w    = (const float*)d_in[6];
    const float* conv_b    = (const float*)d_in[7];
    const float* attn_W    = (const float*)d_in[8];
    const float* attn_V    = (const float*)d_in[9];
    const float* attn_fc_w = (const float*)d_in[10];
    const float* attn_fc_b = (const float*)d_in[11];
    const float* attn_b    = (const float*)d_in[12];
    const float* fc_w      = (const float*)d_in[13];
    const float* fc_b      = (const float*)d_in[14];

    float* ws   = (float*)d_ws;
    float* Vv   = ws;                         // 4,915,200
    float* Z    = Vv + 4915200;               // 25,984 zeros (h0|ctx0|aw0)
    float* hv   = Z + 25984;                  // 64 x 8192
    float* cv   = hv + 524288;                // 64 x 8192
    float* wqv  = cv + 524288;                // 64 x 8192
    float* scv  = wqv + 524288;               // 64 x 9600
    float* awv  = scv + 614400;               // 64 x 9600
    float* pav  = awv + 614400;               // 64 x 16384
    float* logZ = pav + 1048576;              // 1024
    int*   cnt  = (int*)(logZ + 1024);        // 1024 ints
    float* dout = (float*)d_out;

    hipMemsetAsync(Z, 0, 25984 * sizeof(float), stream);
    hipMemsetAsync(cnt, 0, 1024 * sizeof(int), stream);

    k_vv<<<dim3(640), dim3(256), 0, stream>>>(enc, attn_V, Vv);

    void* args[] = {(void*)&enc, (void*)&emb, (void*)&w_ih, (void*)&w_hh,
                    (void*)&b_ih, (void*)&b_hh, (void*)&conv_w, (void*)&conv_b,
                    (void*)&attn_W, (void*)&attn_fc_w, (void*)&attn_fc_b,
                    (void*)&attn_b, (void*)&fc_w, (void*)&fc_b, (void*)&Vv,
                    (void*)&Z, (void*)&hv, (void*)&cv, (void*)&wqv, (void*)&scv,
                    (void*)&awv, (void*)&pav, (void*)&logZ, (void*)&cnt,
                    (void*)&dout};
    hipLaunchCooperativeKernel(reinterpret_cast<void*>(mega),
                               dim3(NG), dim3(NT), args, 0, stream);
}